// Round 3
// baseline (270.822 us; speedup 1.0000x reference)
//
#include <hip/hip_runtime.h>
#include <hip/hip_bf16.h>
#include <stdint.h>

// ---------------------------------------------------------------------------
// SelfAttention: QKV = X@W + b ; S = QK^T/32 (mask -> -inf) ; O = softmax(S)@V
// B=4, S=2048, H=1024.  bf16 MFMA path.
// R11: 8-phase 256-tile schedule (as R10) but LDS buffers are SEPARATE NAMED
//     __shared__ arrays (A0/A1/B0/B1). R10 showed ~750cy/phase stalls with
//     all pipes idle: with one big ls[] + runtime offsets, the compiler's
//     waitcnt pass cannot disambiguate ds_read vs outstanding global_load_lds
//     (LDS-DMA) -> inserts s_waitcnt vmcnt(0) before every ds_read cluster,
//     defeating the counted-vmcnt pipeline (also explains R9 ~= R8).
//     Named arrays give NoAlias -> compiler's precise waits match the
//     intended gates (vmcnt(2)/(6)). V-epilogue reworked into A0 (4 passes).
// ---------------------------------------------------------------------------

typedef __attribute__((ext_vector_type(8))) short bf16x8;   // 8 bf16 = 4 VGPRs
typedef __attribute__((ext_vector_type(4))) float f32x4;

__device__ __forceinline__ void async_cp16(const void* g, void* l) {
  __builtin_amdgcn_global_load_lds(
      (const __attribute__((address_space(1))) void*)g,
      (__attribute__((address_space(3))) void*)l, 16, 0, 0);
}

#define FENCE() asm volatile("" ::: "memory")
#define BAR()                           \
  do {                                  \
    FENCE();                            \
    __builtin_amdgcn_s_barrier();       \
    FENCE();                            \
  } while (0)
#define VMW(N) asm volatile("s_waitcnt vmcnt(" #N ")" ::: "memory")

// --------------------------- fp32 -> bf16 convert ---------------------------
__global__ void cvt_f32_bf16(const float* __restrict__ s,
                             __hip_bfloat16* __restrict__ d, int n) {
  int i = (blockIdx.x * blockDim.x + threadIdx.x) * 4;
  if (i >= n) return;
  float4 f = *(const float4*)(s + i);
  __hip_bfloat16 o[4];
  o[0] = __float2bfloat16(f.x);
  o[1] = __float2bfloat16(f.y);
  o[2] = __float2bfloat16(f.z);
  o[3] = __float2bfloat16(f.w);
  *(ushort4*)(d + i) = *(const ushort4*)o;
}

// -------------------- fp32 -> bf16 transposed (W -> W^T) --------------------
__global__ void transpose_cvt_f32(const float* __restrict__ src, int srcld,
                                  __hip_bfloat16* __restrict__ dst, int dstld) {
  __shared__ float tile[32][33];
  int bx = blockIdx.x * 32;   // src col
  int by = blockIdx.y * 32;   // src row
  int tx = threadIdx.x, ty = threadIdx.y;
#pragma unroll
  for (int j = 0; j < 4; ++j)
    tile[ty + j * 8][tx] = src[(int64_t)(by + ty + j * 8) * srcld + bx + tx];
  __syncthreads();
#pragma unroll
  for (int j = 0; j < 4; ++j)
    dst[(int64_t)(bx + ty + j * 8) * dstld + by + tx] =
        __float2bfloat16(tile[tx][ty + j * 8]);
}

// ------------------------------ mask scan ----------------------------------
__global__ __launch_bounds__(256) void mask_scan(const int* __restrict__ mask,
                                                 int* __restrict__ idx,
                                                 int* __restrict__ cnt,
                                                 int* __restrict__ cnt_pad) {
  const int b = blockIdx.x;
  mask += b * 2048;
  idx += b * 2048;
  const int t = threadIdx.x;
  const int lane = t & 63, wave = t >> 6;

  int keep[8];
  int local = 0;
#pragma unroll
  for (int j = 0; j < 8; ++j) {
    keep[j] = (mask[t * 8 + j] == 0);
    local += keep[j];
  }
  int pre = local;  // inclusive wave scan
#pragma unroll
  for (int off = 1; off <= 32; off <<= 1) {
    int n = __shfl_up(pre, off, 64);
    if (lane >= off) pre += n;
  }
  __shared__ int wsum[4];
  if (lane == 63) wsum[wave] = pre;
  __syncthreads();
  int base = 0;
  for (int w = 0; w < wave; ++w) base += wsum[w];
  int excl = base + pre - local;
#pragma unroll
  for (int j = 0; j < 8; ++j)
    if (keep[j]) idx[excl++] = t * 8 + j;
  if (t == 255) {
    int tot = base + pre;
    cnt[b] = tot;
    int p = (tot + 255) & ~255;     // 256-tile aligned for 8-phase GEMMs
    cnt_pad[b] = p > 2048 ? 2048 : p;
  }
}

// --------------------------- merged Q+K+V GEMM -----------------------------
// grid (96, 1, B), 512 thr.  f<32: Q tiles (8m x 4n); f>=32: KV (8m x 8n).
// BM=BN=256, BK=64, 8 waves (2M x 4N), per-wave C = 128x64.
// LDS 128KB: A0/A1/B0/B1 = [256][64] bf16 each (named arrays for AA).
__global__ __launch_bounds__(512, 2) void gemm_qkv(
    const __hip_bfloat16* __restrict__ Xb, const __hip_bfloat16* __restrict__ Wt,
    const float* __restrict__ bias, const int* __restrict__ idx,
    const int* __restrict__ cnt, const int* __restrict__ cnt_pad,
    __hip_bfloat16* __restrict__ Q, __hip_bfloat16* __restrict__ Kc,
    __hip_bfloat16* __restrict__ Vt) {
  const int z = blockIdx.z;
  const int f = blockIdx.x;
  int m0, n0;
  bool isQ;
  if (f < 32) {
    int xcd = f & 7, loc = f >> 3;
    isQ = true;
    m0 = (loc * 2 + (xcd >> 2)) * 256;
    n0 = (xcd & 3) * 256;
  } else {
    int g = f - 32, xcd = g & 7, loc = g >> 3;
    isQ = false;
    m0 = ((loc & 3) * 2 + (xcd >> 2)) * 256;
    n0 = ((loc >> 2) * 4 + (xcd & 3)) * 256;
  }
  if (!isQ && m0 >= cnt_pad[z]) return;
  const __hip_bfloat16* A = Xb + (int64_t)z * 2048 * 1024;
  const __hip_bfloat16* Bt = Wt + (isQ ? 0 : (int64_t)1024 * 1024);
  const float* bv = bias + (isQ ? 0 : 1024);

  const int tid = threadIdx.x;
  const int wave = tid >> 6, lane = tid & 63;
  const int quad = lane >> 4, tr = lane & 15, t7 = tr & 7;
  const int wm = wave >> 2, wn = wave & 3;

  __shared__ __hip_bfloat16 A0[16384];
  __shared__ __hip_bfloat16 A1[16384];
  __shared__ __hip_bfloat16 B0[16384];
  __shared__ __hip_bfloat16 B1[16384];

  const int srow = lane >> 3;
  const int kcs = ((lane & 7) ^ srow) * 8;   // pre-swizzled k-chunk (elements)

  // Per-wave staging: each half = 16 chunks of 8 rows; 2 chunks/wave/half.
  const __hip_bfloat16* pA[2][2];
  const __hip_bfloat16* pB[2][2];
  int off[2][2];
  {
    const int cz = isQ ? 0 : cnt[z];
    const int* idxz = idx + z * 2048;
#pragma unroll
    for (int h = 0; h < 2; ++h)
#pragma unroll
      for (int j = 0; j < 2; ++j) {
        int chunk = wave * 2 + j;
        int rl = h * 128 + chunk * 8 + srow;
        int ar = m0 + rl;
        if (!isQ) ar = (ar < cz) ? idxz[ar] : 0;
        pA[h][j] = A + (int64_t)ar * 1024 + kcs;
        pB[h][j] = Bt + (int64_t)(n0 + rl) * 1024 + kcs;
        off[h][j] = (h * 128 + chunk * 8) * 64;
      }
  }

  f32x4 acc[8][4];
#pragma unroll
  for (int mi = 0; mi < 8; ++mi)
#pragma unroll
    for (int ni = 0; ni < 4; ++ni) acc[mi][ni] = (f32x4){0.f, 0.f, 0.f, 0.f};

  bf16x8 af[4], bf[4];

#define STA(ARR, h, t)                                \
  do {                                                \
    async_cp16(pA[h][0] + (t) * 64, ARR + off[h][0]); \
    async_cp16(pA[h][1] + (t) * 64, ARR + off[h][1]); \
  } while (0)
#define STB(ARR, h, t)                                \
  do {                                                \
    async_cp16(pB[h][0] + (t) * 64, ARR + off[h][0]); \
    async_cp16(pB[h][1] + (t) * 64, ARR + off[h][1]); \
  } while (0)
#define DSA(ARR, h, s)                                                        \
  do {                                                                        \
    _Pragma("unroll") for (int j = 0; j < 4; ++j) af[j] =                     \
        *(const bf16x8*)(ARR + (wm * 128 + (h)*64 + j * 16 + tr) * 64 +       \
                         ((((s) << 2) | quad) ^ t7) * 8);                     \
  } while (0)
#define DSB(ARR, s)                                                           \
  do {                                                                        \
    _Pragma("unroll") for (int n = 0; n < 4; ++n) bf[n] =                     \
        *(const bf16x8*)(ARR + (wn * 64 + n * 16 + tr) * 64 +                 \
                         ((((s) << 2) | quad) ^ t7) * 8);                     \
  } while (0)
#define MF(h)                                                                 \
  do {                                                                        \
    __builtin_amdgcn_s_setprio(1);                                            \
    _Pragma("unroll") for (int j = 0; j < 4; ++j)                             \
        _Pragma("unroll") for (int n = 0; n < 4; ++n) acc[(h)*4 + j][n] =     \
            __builtin_amdgcn_mfma_f32_16x16x32_bf16(af[j], bf[n],             \
                                                    acc[(h)*4 + j][n], 0, 0,  \
                                                    0);                       \
    __builtin_amdgcn_s_setprio(0);                                            \
  } while (0)

  // Prologue: buf0 = tile0 (4 halves), B1-h0 = tile1.
  STA(A0, 0, 0); STA(A0, 1, 0); STB(B0, 0, 0); STB(B0, 1, 0);
  STB(B1, 0, 1);
  VMW(2);
  BAR();

  for (int it = 0; it < 8; ++it) {   // NT=16 K-tiles, 2 per iteration
    const int t1 = 2 * it + 1;
    const int tn0 = (2 * it + 2 < 16) ? 2 * it + 2 : 15;
    const int tn1 = (2 * it + 3 < 16) ? 2 * it + 3 : 15;
    DSA(A0, 0, 0); DSB(B0, 0); STB(B1, 1, t1);  BAR(); MF(0); BAR();
    DSA(A0, 1, 0);             STA(A1, 0, t1);  BAR(); MF(1); BAR();
    DSA(A0, 0, 1); DSB(B0, 1); STA(A1, 1, t1);  BAR(); MF(0); BAR();
    DSA(A0, 1, 1);             STB(B0, 0, tn0); VMW(2); BAR(); MF(1); BAR();
    DSA(A1, 0, 0); DSB(B1, 0); STB(B0, 1, tn0); BAR(); MF(0); BAR();
    DSA(A1, 1, 0);             STA(A0, 0, tn0); BAR(); MF(1); BAR();
    DSA(A1, 0, 1); DSB(B1, 1); STA(A0, 1, tn0); BAR(); MF(0); BAR();
    DSA(A1, 1, 1);             STB(B1, 0, tn1); VMW(2); BAR(); MF(1); BAR();
  }
  asm volatile("s_waitcnt vmcnt(0)" ::: "memory");  // drain stray tail stages
#undef STA
#undef STB
#undef DSA
#undef DSB
#undef MF

  // Epilogue. D element (row,col) in 16x16 tile = (quad*4 + r, tr)  [m89]
  const int rowbase = m0 + wm * 128;
  const int colbase = n0 + wn * 64;
  if (isQ) {
    __hip_bfloat16* C = Q + (int64_t)z * 2048 * 1024;
#pragma unroll
    for (int ni = 0; ni < 4; ++ni) {
      int col = colbase + ni * 16 + tr;
      float bb = bv[col];
#pragma unroll
      for (int mi = 0; mi < 8; ++mi) {
        int row = rowbase + mi * 16 + quad * 4;
#pragma unroll
        for (int r = 0; r < 4; ++r)
          C[(int64_t)(row + r) * 1024 + col] =
              __float2bfloat16(acc[mi][ni][r] + bb);
      }
    }
  } else if (n0 < 1024) {  // K half
    __hip_bfloat16* C = Kc + (int64_t)z * 2048 * 1024;
#pragma unroll
    for (int ni = 0; ni < 4; ++ni) {
      int col = colbase + ni * 16 + tr;
      float bb = bv[col];
#pragma unroll
      for (int mi = 0; mi < 8; ++mi) {
        int row = rowbase + mi * 16 + quad * 4;
#pragma unroll
        for (int r = 0; r < 4; ++r)
          C[(int64_t)(row + r) * 1024 + col] =
              __float2bfloat16(acc[mi][ni][r] + bb);
      }
    }
  } else {  // V half -> LDS transpose in A0 (4 passes of 64 d-cols) -> Vt
    __hip_bfloat16* Vz = Vt + (int64_t)z * 1024 * 2048;
    const int d0 = n0 - 1024;
#pragma unroll
    for (int p = 0; p < 4; ++p) {
      __syncthreads();
      if (wn == p) {  // the 2 waves (wm=0,1) owning d-cols [p*64, p*64+64)
#pragma unroll
        for (int ni = 0; ni < 4; ++ni) {
          int cl = ni * 16 + tr;                       // pass-local d [0,64)
          float bb = bv[colbase + ni * 16 + tr];
#pragma unroll
          for (int mi = 0; mi < 8; ++mi) {
            int rl = wm * 128 + mi * 16 + quad * 4;    // block-local key
            __hip_bfloat16 h4[4];
#pragma unroll
            for (int r = 0; r < 4; ++r)
              h4[r] = __float2bfloat16(acc[mi][ni][r] + bb);
            *(ushort4*)(A0 + cl * 256 + (rl ^ ((cl & 31) << 3))) =
                *(const ushort4*)h4;
          }
        }
      }
      __syncthreads();
      const int dloc = tid >> 3;   // [0,64)
      const int sg = tid & 7;
#pragma unroll
      for (int i = 0; i < 4; ++i) {
        int seg = i * 8 + sg;      // [0,32) -> keys seg*8..seg*8+7
        bf16x8 v =
            *(const bf16x8*)(A0 + dloc * 256 + ((seg * 8) ^ ((dloc & 31) << 3)));
        *(bf16x8*)(Vz + (int64_t)(d0 + p * 64 + dloc) * 2048 + m0 + seg * 8) =
            v;
      }
    }
  }
}

// ------------------------ scores GEMM + fused exp --------------------------
// e = exp2(scale2 * (Q@Kc^T)) bf16; cols >= cnt -> 0. Row sums -> atomicAdd.
// BM=256, BN=128, BK=64, 8 waves (2M x 4N), per-wave C = 128x32.
// LDS 96KB: A0/A1=[256][64], B0/B1=[128][64] (named arrays for AA).
__global__ __launch_bounds__(512, 2) void gemm_scores(
    const __hip_bfloat16* __restrict__ Qb, const __hip_bfloat16* __restrict__ Kc,
    __hip_bfloat16* __restrict__ Sc, float* __restrict__ rowsum,
    const int* __restrict__ cnt, const int* __restrict__ cnt_pad,
    float scale2) {
  const int z = blockIdx.z;
  const int f = blockIdx.x;
  const int xcd = f & 7, loc = f >> 3;
  const int m0 = (loc & 7) * 256;
  const int n0 = ((loc >> 3) * 8 + xcd) * 128;
  if (n0 >= cnt_pad[z]) return;
  const __hip_bfloat16* A = Qb + (int64_t)z * 2048 * 1024;
  const __hip_bfloat16* Bt = Kc + (int64_t)z * 2048 * 1024;

  const int tid = threadIdx.x;
  const int wave = tid >> 6, lane = tid & 63;
  const int quad = lane >> 4, tr = lane & 15, t7 = tr & 7;
  const int wm = wave >> 2, wn = wave & 3;

  __shared__ __hip_bfloat16 A0[16384];
  __shared__ __hip_bfloat16 A1[16384];
  __shared__ __hip_bfloat16 B0[8192];
  __shared__ __hip_bfloat16 B1[8192];

  const int srow = lane >> 3;
  const int kcs = ((lane & 7) ^ srow) * 8;

  const __hip_bfloat16* pA[2][2];
  const __hip_bfloat16* pB[2];
  int aoff[2][2], boff[2];
  {
#pragma unroll
    for (int h = 0; h < 2; ++h) {
#pragma unroll
      for (int j = 0; j < 2; ++j) {
        int chunk = wave * 2 + j;
        int rl = h * 128 + chunk * 8 + srow;
        pA[h][j] = A + (int64_t)(m0 + rl) * 1024 + kcs;
        aoff[h][j] = (h * 128 + chunk * 8) * 64;
      }
      int rlb = h * 64 + wave * 8 + srow;
      pB[h] = Bt + (int64_t)(n0 + rlb) * 1024 + kcs;
      boff[h] = (h * 64 + wave * 8) * 64;
    }
  }

  f32x4 acc[8][2];
#pragma unroll
  for (int mi = 0; mi < 8; ++mi)
#pragma unroll
    for (int ni = 0; ni < 2; ++ni) acc[mi][ni] = (f32x4){0.f, 0.f, 0.f, 0.f};

  bf16x8 af[4], bf[2];

#define STA(ARR, h, t)                                 \
  do {                                                 \
    async_cp16(pA[h][0] + (t) * 64, ARR + aoff[h][0]); \
    async_cp16(pA[h][1] + (t) * 64, ARR + aoff[h][1]); \
  } while (0)
#define STB(ARR, h, t) async_cp16(pB[h] + (t) * 64, ARR + boff[h])
#define DSA(ARR, h, s)                                                        \
  do {                                                                        \
    _Pragma("unroll") for (int j = 0; j < 4; ++j) af[j] =                     \
        *(const bf16x8*)(ARR + (wm * 128 + (h)*64 + j * 16 + tr) * 64 +       \
                         ((((s) << 2) | quad) ^ t7) * 8);                     \
  } while (0)
#define DSB(ARR, s)                                                           \
  do {                                                                        \
    _Pragma("unroll") for (int n = 0; n < 2; ++n) bf[n] =                     \
        *(const bf16x8*)(ARR + (wn * 32 + n * 16 + tr) * 64 +                 \
                         ((((s) << 2) | quad) ^ t7) * 8);                     \
  } while (0)
#define MF(h)                                                                 \
  do {                                                                        \
    __builtin_amdgcn_s_setprio(1);                                            \
    _Pragma("unroll") for (int j = 0; j < 4; ++j)                             \
        _Pragma("unroll") for (int n = 0; n < 2; ++n) acc[(h)*4 + j][n] =     \
            __builtin_amdgcn_mfma_f32_16x16x32_bf16(af[j], bf[n],             \
                                                    acc[(h)*4 + j][n], 0, 0,  \
                                                    0);                       \
    __builtin_amdgcn_s_setprio(0);                                            \
  } while (0)

  STA(A0, 0, 0); STA(A0, 1, 0); STB(B0, 0, 0); STB(B0, 1, 0);
  STB(B1, 0, 1);
  VMW(1);
  BAR();

  for (int it = 0; it < 8; ++it) {
    const int t1 = 2 * it + 1;
    const int tn0 = (2 * it + 2 < 16) ? 2 * it + 2 : 15;
    const int tn1 = (2 * it + 3 < 16) ? 2 * it + 3 : 15;
    DSA(A0, 0, 0); DSB(B0, 0); STB(B1, 1, t1);  BAR(); MF(0); BAR();
    DSA(A0, 1, 0);             STA(A1, 0, t1);  BAR(); MF(1); BAR();
    DSA(A0, 0, 1); DSB(B0, 1); STA(A1, 1, t1);  BAR(); MF(0); BAR();
    DSA(A0, 1, 1);             STB(B0, 0, tn0); VMW(1); BAR(); MF(1); BAR();
    DSA(A1, 0, 0); DSB(B1, 0); STB(B0, 1, tn0); BAR(); MF(0); BAR();
    DSA(A1, 1, 0);             STA(A0, 0, tn0); BAR(); MF(1); BAR();
    DSA(A1, 0, 1); DSB(B1, 1); STA(A0, 1, tn0); BAR(); MF(0); BAR();
    DSA(A1, 1, 1);             STB(B1, 0, tn1); VMW(1); BAR(); MF(1); BAR();
  }
  asm volatile("s_waitcnt vmcnt(0)" ::: "memory");
#undef STA
#undef STB
#undef DSA
#undef DSB
#undef MF

  const int rowbase = m0 + wm * 128;
  const int colbase = n0 + wn * 32;
  const int cn = cnt[z];
  __hip_bfloat16* C = Sc + (int64_t)z * 2048 * 2048;

  float psum[8][4];
#pragma unroll
  for (int mi = 0; mi < 8; ++mi)
#pragma unroll
    for (int r = 0; r < 4; ++r) psum[mi][r] = 0.f;

#pragma unroll
  for (int ni = 0; ni < 2; ++ni) {
    int col = colbase + ni * 16 + tr;
    bool valid = (col < cn);
#pragma unroll
    for (int mi = 0; mi < 8; ++mi) {
      int row = rowbase + mi * 16 + quad * 4;
#pragma unroll
      for (int r = 0; r < 4; ++r) {
        float e = valid ? exp2f(acc[mi][ni][r] * scale2) : 0.f;
        C[(int64_t)(row + r) * 2048 + col] = __float2bfloat16(e);
        psum[mi][r] += e;
      }
    }
  }
#pragma unroll
  for (int off = 1; off <= 8; off <<= 1)
#pragma unroll
    for (int mi = 0; mi < 8; ++mi)
#pragma unroll
      for (int r = 0; r < 4; ++r)
        psum[mi][r] += __shfl_xor(psum[mi][r], off, 64);
  if (tr == 0) {
    float* rs = rowsum + z * 2048 + rowbase;
#pragma unroll
    for (int mi = 0; mi < 8; ++mi)
#pragma unroll
      for (int r = 0; r < 4; ++r)
        atomicAdd(&rs[mi * 16 + quad * 4 + r], psum[mi][r]);
  }
}

// --------------------------- PV GEMM + normalize ---------------------------
// out = (E @ Vt^T) / rowsum[row]  (fp32). K = cnt_pad[z]. BM=256, BN=128.
__global__ __launch_bounds__(512, 2) void gemm_pv(
    const __hip_bfloat16* __restrict__ Sc, const __hip_bfloat16* __restrict__ Vt,
    float* __restrict__ out, const float* __restrict__ rowsum,
    const int* __restrict__ cnt_pad) {
  const int z = blockIdx.z;
  const int f = blockIdx.x;
  const int m0 = (f >> 3) * 256;
  const int n0 = (f & 7) * 128;
  const int Ks = cnt_pad[z];
  const __hip_bfloat16* A = Sc + (int64_t)z * 2048 * 2048;
  const __hip_bfloat16* Bt = Vt + (int64_t)z * 1024 * 2048;

  const int tid = threadIdx.x;
  const int wave = tid >> 6, lane = tid & 63;
  const int quad = lane >> 4, tr = lane & 15, t7 = tr & 7;
  const int wm = wave >> 2, wn = wave & 3;

  __shared__ __hip_bfloat16 A0[16384];
  __shared__ __hip_bfloat16 A1[16384];
  __shared__ __hip_bfloat16 B0[8192];
  __shared__ __hip_bfloat16 B1[8192];

  const int srow = lane >> 3;
  const int kcs = ((lane & 7) ^ srow) * 8;

  const __hip_bfloat16* pA[2][2];
  const __hip_bfloat16* pB[2];
  int aoff[2][2], boff[2];
  {
#pragma unroll
    for (int h = 0; h < 2; ++h) {
#pragma unroll
      for (int j = 0; j < 2; ++j) {
        int chunk = wave * 2 + j;
        int rl = h * 128 + chunk * 8 + srow;
        pA[h][j] = A + (int64_t)(m0 + rl) * 2048 + kcs;
        aoff[h][j] = (h * 128 + chunk * 8) * 64;
      }
      int rlb = h * 64 + wave * 8 + srow;
      pB[h] = Bt + (int64_t)(n0 + rlb) * 2048 + kcs;
      boff[h] = (h * 64 + wave * 8) * 64;
    }
  }

  f32x4 acc[8][2];
#pragma unroll
  for (int mi = 0; mi < 8; ++mi)
#pragma unroll
    for (int ni = 0; ni < 2; ++ni) acc[mi][ni] = (f32x4){0.f, 0.f, 0.f, 0.f};

  bf16x8 af[4], bf[2];

#define STA(ARR, h, t)                                 \
  do {                                                 \
    async_cp16(pA[h][0] + (t) * 64, ARR + aoff[h][0]); \
    async_cp16(pA[h][1] + (t) * 64, ARR + aoff[h][1]); \
  } while (0)
#define STB(ARR, h, t) async_cp16(pB[h] + (t) * 64, ARR + boff[h])
#define DSA(ARR, h, s)                                                        \
  do {                                                                        \
    _Pragma("unroll") for (int j = 0; j < 4; ++j) af[j] =                     \
        *(const bf16x8*)(ARR + (wm * 128 + (h)*64 + j * 16 + tr) * 64 +       \
                         ((((s) << 2) | quad) ^ t7) * 8);                     \
  } while (0)
#define DSB(ARR, s)                                                           \
  do {                                                                        \
    _Pragma("unroll") for (int n = 0; n < 2; ++n) bf[n] =                     \
        *(const bf16x8*)(ARR + (wn * 32 + n * 16 + tr) * 64 +                 \
                         ((((s) << 2) | quad) ^ t7) * 8);                     \
  } while (0)
#define MF(h)                                                                 \
  do {                                                                        \
    __builtin_amdgcn_s_setprio(1);                                            \
    _Pragma("unroll") for (int j = 0; j < 4; ++j)                             \
        _Pragma("unroll") for (int n = 0; n < 2; ++n) acc[(h)*4 + j][n] =     \
            __builtin_amdgcn_mfma_f32_16x16x32_bf16(af[j], bf[n],             \
                                                    acc[(h)*4 + j][n], 0, 0,  \
                                                    0);                       \
    __builtin_amdgcn_s_setprio(0);                                            \
  } while (0)

  const int NT = Ks >> 6;       // K-tiles (multiple of 4)
  const int NITER = NT >> 1;
  const int NTm1 = NT - 1;

  STA(A0, 0, 0); STA(A0, 1, 0); STB(B0, 0, 0); STB(B0, 1, 0);
  STB(B1, 0, 1);
  VMW(1);
  BAR();

  for (int it = 0; it < NITER; ++it) {
    const int t1 = 2 * it + 1;
    const int tn0 = (2 * it + 2 > NTm1) ? NTm1 : 2 * it + 2;
    const int tn1 = (2 * it + 3 > NTm1) ? NTm1 : 2 * it + 3;
    DSA(A0, 0, 0); DSB(B0, 0); STB(B1, 1, t1);  BAR(); MF(0); BAR();
    DSA(A0, 1, 0);             STA(A1, 0, t1);  BAR(); MF(1); BAR();
    DSA(A0, 0, 1); DSB(B0, 1); STA(A1, 1, t1);  BAR(); MF(0); BAR();
    DSA(A0, 1, 1);             STB(B0, 0, tn0); VMW(1); BAR(); MF(1); BAR();
    DSA(A1, 0, 0); DSB(B1, 0); STB(B0, 1, tn0); BAR(); MF(0); BAR();
    DSA(A1, 1, 0);             STA(A0, 0, tn0); BAR(); MF(1); BAR();
    DSA(A1, 0, 1); DSB(B1, 1); STA(A0, 1, tn0); BAR(); MF(0); BAR();
    DSA(A1, 1, 1);             STB(B1, 0, tn1); VMW(1); BAR(); MF(1); BAR();
  }
  asm volatile("s_waitcnt vmcnt(0)" ::: "memory");
#undef STA
#undef STB
#undef DSA
#undef DSB
#undef MF

  const int rowbase = m0 + wm * 128;
  const int colbase = n0 + wn * 32;
  const float* rs = rowsum + z * 2048 + rowbase;
  float invv[8][4];
#pragma unroll
  for (int mi = 0; mi < 8; ++mi)
#pragma unroll
    for (int r = 0; r < 4; ++r) invv[mi][r] = 1.0f / rs[mi * 16 + quad * 4 + r];

  float* C = out + (int64_t)z * 2048 * 1024;
#pragma unroll
  for (int ni = 0; ni < 2; ++ni) {
    int col = colbase + ni * 16 + tr;
#pragma unroll
    for (int mi = 0; mi < 8; ++mi) {
      int row = rowbase + mi * 16 + quad * 4;
#pragma unroll
      for (int r = 0; r < 4; ++r)
        C[(int64_t)(row + r) * 1024 + col] = acc[mi][ni][r] * invv[mi][r];
    }
  }
}

// ------------------------------- launcher ----------------------------------
extern "C" void kernel_launch(void* const* d_in, const int* in_sizes, int n_in,
                              void* d_out, int out_size, void* d_ws,
                              size_t ws_size, hipStream_t stream) {
  const float* X = (const float*)d_in[0];        // (4,2048,1024) fp32
  const int* mask = (const int*)d_in[1];         // (4,2048) bool->int32
  const float* W = (const float*)d_in[2];        // (1024,3072) fp32
  const float* bias = (const float*)d_in[3];     // (3072,) fp32
  float* out = (float*)d_out;                    // (4,2048,1024) fp32

  char* ws = (char*)d_ws;
  auto alloc = [&](size_t bytes) {
    char* p = ws;
    ws += (bytes + 255) & ~(size_t)255;
    return p;
  };
  __hip_bfloat16* Xb = (__hip_bfloat16*)alloc(8192ULL * 1024 * 2);      // 16.8 MB
  __hip_bfloat16* Wt = (__hip_bfloat16*)alloc(3072ULL * 1024 * 2);      //  6.3 MB
  __hip_bfloat16* Q = (__hip_bfloat16*)alloc(8192ULL * 1024 * 2);       // 16.8 MB
  __hip_bfloat16* Kc = (__hip_bfloat16*)alloc(4ULL * 2048 * 1024 * 2);  // 16.8 MB
  __hip_bfloat16* Vt = (__hip_bfloat16*)alloc(4ULL * 1024 * 2048 * 2);  // 16.8 MB
  __hip_bfloat16* Sc = (__hip_bfloat16*)alloc(4ULL * 2048 * 2048 * 2);  // 33.6 MB
  float* rowsum = (float*)alloc(8192ULL * 4);                           // 32 KB
  int* idx = (int*)alloc(4ULL * 2048 * 4);
  int* cnt = (int*)alloc(64);
  int* cnt_pad = (int*)alloc(64);

  // 0) rowsum = 0 (ws is poisoned 0xAA before every launch)
  hipMemsetAsync(rowsum, 0, 8192ULL * 4, stream);
  // 1) X -> bf16
  cvt_f32_bf16<<<8192, 256, 0, stream>>>(X, Xb, 8192 * 1024);
  // 2) W -> W^T bf16  (Bt layout [N][K])
  transpose_cvt_f32<<<dim3(96, 32, 1), dim3(32, 8), 0, stream>>>(W, 3072, Wt,
                                                                 1024);
  // 3) mask -> compacted index list (cnt_pad 256-aligned)
  mask_scan<<<4, 256, 0, stream>>>(mask, idx, cnt, cnt_pad);
  // 4) merged Q + K + V^T, 256x256 8-phase
  gemm_qkv<<<dim3(96, 1, 4), 512, 0, stream>>>(Xb, Wt, bias, idx, cnt,
                                               cnt_pad, Q, Kc, Vt);
  // 5) E = exp2(log2e/32 * Q@Kc^T) -> bf16, rowsum += per-row sums
  gemm_scores<<<dim3(128, 1, 4), 512, 0, stream>>>(
      Q, Kc, Sc, rowsum, cnt, cnt_pad, 0.03125f * 1.4426950408889634f);
  // 6) out = (E @ Vt^T) / rowsum  (fp32, K = cnt_pad)
  gemm_pv<<<dim3(64, 1, 4), 512, 0, stream>>>(Sc, Vt, out, rowsum, cnt_pad);
}

// Round 4
// 237.952 us; speedup vs baseline: 1.1381x; 1.1381x over previous
//
#include <hip/hip_runtime.h>
#include <hip/hip_bf16.h>
#include <stdint.h>

// ---------------------------------------------------------------------------
// SelfAttention: QKV = X@W + b ; S = QK^T/32 (mask -> -inf) ; O = softmax(S)@V
// B=4, S=2048, H=1024.  bf16 MFMA path.
// R12: 8-phase 256-tile schedule (as R11) but ALL fragment LDS reads are
//     inline-asm ds_read_b128 (register-only constraints). R10/R11 showed
//     ~1460cy/phase = full latency drain every phase: the compiler inserts
//     s_waitcnt vmcnt(0) before any compiler-visible ds_read that may alias
//     an outstanding global_load_lds (named arrays did not help). With asm
//     reads the waitcnt pass sees no LDS access -> no implicit waits; the
//     ONLY DMA gates are my counted vmcnt(2)/(1) at ph4/ph8. Ordering is
//     enforced per template + rule #18: per phase
//     {asm ds_reads | stage -> BAR -> lgkmcnt(0) -> sched_barrier(0) ->
//      setprio(1) MFMA setprio(0) -> BAR}.
//     Read-after-DMA and restage-after-read distances re-derived by hand.
// ---------------------------------------------------------------------------

typedef __attribute__((ext_vector_type(8))) short bf16x8;   // 8 bf16 = 4 VGPRs
typedef __attribute__((ext_vector_type(4))) float f32x4;

__device__ __forceinline__ void async_cp16(const void* g, void* l) {
  __builtin_amdgcn_global_load_lds(
      (const __attribute__((address_space(1))) void*)g,
      (__attribute__((address_space(3))) void*)l, 16, 0, 0);
}

__device__ __forceinline__ uint32_t laddr(const void* p) {
  return (uint32_t)(uintptr_t)(const __attribute__((address_space(3))) void*)p;
}

#define FENCE() asm volatile("" ::: "memory")
#define BAR()                           \
  do {                                  \
    FENCE();                            \
    __builtin_amdgcn_s_barrier();       \
    FENCE();                            \
  } while (0)
#define VMW(N) asm volatile("s_waitcnt vmcnt(" #N ")" ::: "memory")

// asm ds_read_b128 with literal byte offset; no memory operand on purpose.
#define DSR(dst, a, OFF) \
  asm volatile("ds_read_b128 %0, %1 offset:" #OFF : "=v"(dst) : "v"(a))

// --------------------------- fp32 -> bf16 convert ---------------------------
__global__ void cvt_f32_bf16(const float* __restrict__ s,
                             __hip_bfloat16* __restrict__ d, int n) {
  int i = (blockIdx.x * blockDim.x + threadIdx.x) * 4;
  if (i >= n) return;
  float4 f = *(const float4*)(s + i);
  __hip_bfloat16 o[4];
  o[0] = __float2bfloat16(f.x);
  o[1] = __float2bfloat16(f.y);
  o[2] = __float2bfloat16(f.z);
  o[3] = __float2bfloat16(f.w);
  *(ushort4*)(d + i) = *(const ushort4*)o;
}

// -------------------- fp32 -> bf16 transposed (W -> W^T) --------------------
__global__ void transpose_cvt_f32(const float* __restrict__ src, int srcld,
                                  __hip_bfloat16* __restrict__ dst, int dstld) {
  __shared__ float tile[32][33];
  int bx = blockIdx.x * 32;   // src col
  int by = blockIdx.y * 32;   // src row
  int tx = threadIdx.x, ty = threadIdx.y;
#pragma unroll
  for (int j = 0; j < 4; ++j)
    tile[ty + j * 8][tx] = src[(int64_t)(by + ty + j * 8) * srcld + bx + tx];
  __syncthreads();
#pragma unroll
  for (int j = 0; j < 4; ++j)
    dst[(int64_t)(bx + ty + j * 8) * dstld + by + tx] =
        __float2bfloat16(tile[tx][ty + j * 8]);
}

// ------------------------------ mask scan ----------------------------------
__global__ __launch_bounds__(256) void mask_scan(const int* __restrict__ mask,
                                                 int* __restrict__ idx,
                                                 int* __restrict__ cnt,
                                                 int* __restrict__ cnt_pad) {
  const int b = blockIdx.x;
  mask += b * 2048;
  idx += b * 2048;
  const int t = threadIdx.x;
  const int lane = t & 63, wave = t >> 6;

  int keep[8];
  int local = 0;
#pragma unroll
  for (int j = 0; j < 8; ++j) {
    keep[j] = (mask[t * 8 + j] == 0);
    local += keep[j];
  }
  int pre = local;  // inclusive wave scan
#pragma unroll
  for (int off = 1; off <= 32; off <<= 1) {
    int n = __shfl_up(pre, off, 64);
    if (lane >= off) pre += n;
  }
  __shared__ int wsum[4];
  if (lane == 63) wsum[wave] = pre;
  __syncthreads();
  int base = 0;
  for (int w = 0; w < wave; ++w) base += wsum[w];
  int excl = base + pre - local;
#pragma unroll
  for (int j = 0; j < 8; ++j)
    if (keep[j]) idx[excl++] = t * 8 + j;
  if (t == 255) {
    int tot = base + pre;
    cnt[b] = tot;
    int p = (tot + 255) & ~255;     // 256-tile aligned for 8-phase GEMMs
    cnt_pad[b] = p > 2048 ? 2048 : p;
  }
}

// --------------------------- merged Q+K+V GEMM -----------------------------
// grid (96, 1, B), 512 thr.  f<32: Q tiles (8m x 4n); f>=32: KV (8m x 8n).
// BM=BN=256, BK=64, 8 waves (2M x 4N), per-wave C = 128x64.
// LDS 128KB: A0/A1/B0/B1 = [256][64] bf16 each.
__global__ __launch_bounds__(512, 2) void gemm_qkv(
    const __hip_bfloat16* __restrict__ Xb, const __hip_bfloat16* __restrict__ Wt,
    const float* __restrict__ bias, const int* __restrict__ idx,
    const int* __restrict__ cnt, const int* __restrict__ cnt_pad,
    __hip_bfloat16* __restrict__ Q, __hip_bfloat16* __restrict__ Kc,
    __hip_bfloat16* __restrict__ Vt) {
  const int z = blockIdx.z;
  const int f = blockIdx.x;
  int m0, n0;
  bool isQ;
  if (f < 32) {
    int xcd = f & 7, loc = f >> 3;
    isQ = true;
    m0 = (loc * 2 + (xcd >> 2)) * 256;
    n0 = (xcd & 3) * 256;
  } else {
    int g = f - 32, xcd = g & 7, loc = g >> 3;
    isQ = false;
    m0 = ((loc & 3) * 2 + (xcd >> 2)) * 256;
    n0 = ((loc >> 2) * 4 + (xcd & 3)) * 256;
  }
  if (!isQ && m0 >= cnt_pad[z]) return;
  const __hip_bfloat16* A = Xb + (int64_t)z * 2048 * 1024;
  const __hip_bfloat16* Bt = Wt + (isQ ? 0 : (int64_t)1024 * 1024);
  const float* bv = bias + (isQ ? 0 : 1024);

  const int tid = threadIdx.x;
  const int wave = tid >> 6, lane = tid & 63;
  const int quad = lane >> 4, tr = lane & 15, t7 = tr & 7;
  const int wm = wave >> 2, wn = wave & 3;

  __shared__ __hip_bfloat16 A0[16384];
  __shared__ __hip_bfloat16 A1[16384];
  __shared__ __hip_bfloat16 B0[16384];
  __shared__ __hip_bfloat16 B1[16384];

  const int srow = lane >> 3;
  const int kcs = ((lane & 7) ^ srow) * 8;   // pre-swizzled k-chunk (elements)

  // Per-wave staging: each half = 16 chunks of 8 rows; 2 chunks/wave/half.
  const __hip_bfloat16* pA[2][2];
  const __hip_bfloat16* pB[2][2];
  int off[2][2];
  {
    const int cz = isQ ? 0 : cnt[z];
    const int* idxz = idx + z * 2048;
#pragma unroll
    for (int h = 0; h < 2; ++h)
#pragma unroll
      for (int j = 0; j < 2; ++j) {
        int chunk = wave * 2 + j;
        int rl = h * 128 + chunk * 8 + srow;
        int ar = m0 + rl;
        if (!isQ) ar = (ar < cz) ? idxz[ar] : 0;
        pA[h][j] = A + (int64_t)ar * 1024 + kcs;
        pB[h][j] = Bt + (int64_t)(n0 + rl) * 1024 + kcs;
        off[h][j] = (h * 128 + chunk * 8) * 64;
      }
  }

  // Precomputed LDS byte addresses for asm ds_reads.
  // A frag row base: (wm*128 + h*64 + tr)*64 el *2B; col: ((s<<2|quad)^t7)*16B
  // read offsets j*16*64*2 = j*2048.  B frag rows: (wn*64 + tr), offs n*2048.
  uint32_t aAd[2][2][2], bBd[2][2];
  {
    const uint32_t ab[2] = {laddr(A0), laddr(A1)};
    const uint32_t bb[2] = {laddr(B0), laddr(B1)};
#pragma unroll
    for (int buf = 0; buf < 2; ++buf)
#pragma unroll
      for (int s = 0; s < 2; ++s) {
        uint32_t col = (uint32_t)((((s << 2) | quad) ^ t7) * 16);
#pragma unroll
        for (int h = 0; h < 2; ++h)
          aAd[buf][h][s] = ab[buf] + (wm * 128 + h * 64 + tr) * 128 + col;
        bBd[buf][s] = bb[buf] + (wn * 64 + tr) * 128 + col;
      }
  }

  f32x4 acc[8][4];
#pragma unroll
  for (int mi = 0; mi < 8; ++mi)
#pragma unroll
    for (int ni = 0; ni < 4; ++ni) acc[mi][ni] = (f32x4){0.f, 0.f, 0.f, 0.f};

  bf16x8 af[4], bf[4];

#define STA(ARR, h, t)                                \
  do {                                                \
    async_cp16(pA[h][0] + (t) * 64, ARR + off[h][0]); \
    async_cp16(pA[h][1] + (t) * 64, ARR + off[h][1]); \
  } while (0)
#define STB(ARR, h, t)                                \
  do {                                                \
    async_cp16(pB[h][0] + (t) * 64, ARR + off[h][0]); \
    async_cp16(pB[h][1] + (t) * 64, ARR + off[h][1]); \
  } while (0)
#define DSA(buf, h, s)                      \
  do {                                      \
    DSR(af[0], aAd[buf][h][s], 0);          \
    DSR(af[1], aAd[buf][h][s], 2048);       \
    DSR(af[2], aAd[buf][h][s], 4096);       \
    DSR(af[3], aAd[buf][h][s], 6144);       \
  } while (0)
#define DSB(buf, s)                         \
  do {                                      \
    DSR(bf[0], bBd[buf][s], 0);             \
    DSR(bf[1], bBd[buf][s], 2048);          \
    DSR(bf[2], bBd[buf][s], 4096);          \
    DSR(bf[3], bBd[buf][s], 6144);          \
  } while (0)
#define MF(h)                                                                 \
  do {                                                                        \
    asm volatile("s_waitcnt lgkmcnt(0)" ::: "memory");                        \
    __builtin_amdgcn_sched_barrier(0);                                        \
    __builtin_amdgcn_s_setprio(1);                                            \
    _Pragma("unroll") for (int j = 0; j < 4; ++j)                             \
        _Pragma("unroll") for (int n = 0; n < 4; ++n) acc[(h)*4 + j][n] =     \
            __builtin_amdgcn_mfma_f32_16x16x32_bf16(af[j], bf[n],             \
                                                    acc[(h)*4 + j][n], 0, 0,  \
                                                    0);                       \
    __builtin_amdgcn_s_setprio(0);                                            \
  } while (0)

  // Prologue: buf0 = tile0 (4 halves), B1-h0 = tile1.
  STA(A0, 0, 0); STA(A0, 1, 0); STB(B0, 0, 0); STB(B0, 1, 0);
  STB(B1, 0, 1);
  VMW(2);
  BAR();

  for (int it = 0; it < 8; ++it) {   // NT=16 K-tiles, 2 per iteration
    const int t1 = 2 * it + 1;
    const int tn0 = (2 * it + 2 < 16) ? 2 * it + 2 : 15;
    const int tn1 = (2 * it + 3 < 16) ? 2 * it + 3 : 15;
    DSA(0, 0, 0); DSB(0, 0); STB(B1, 1, t1);  BAR(); MF(0); BAR();
    DSA(0, 1, 0);            STA(A1, 0, t1);  BAR(); MF(1); BAR();
    DSA(0, 0, 1); DSB(0, 1); STA(A1, 1, t1);  BAR(); MF(0); BAR();
    DSA(0, 1, 1);            STB(B0, 0, tn0); VMW(2); BAR(); MF(1); BAR();
    DSA(1, 0, 0); DSB(1, 0); STB(B0, 1, tn0); BAR(); MF(0); BAR();
    DSA(1, 1, 0);            STA(A0, 0, tn0); BAR(); MF(1); BAR();
    DSA(1, 0, 1); DSB(1, 1); STA(A0, 1, tn0); BAR(); MF(0); BAR();
    DSA(1, 1, 1);            STB(B1, 0, tn1); VMW(2); BAR(); MF(1); BAR();
  }
  asm volatile("s_waitcnt vmcnt(0)" ::: "memory");  // drain stray tail stages
  BAR();
#undef STA
#undef STB
#undef DSA
#undef DSB
#undef MF

  // Epilogue. D element (row,col) in 16x16 tile = (quad*4 + r, tr)  [m89]
  const int rowbase = m0 + wm * 128;
  const int colbase = n0 + wn * 64;
  if (isQ) {
    __hip_bfloat16* C = Q + (int64_t)z * 2048 * 1024;
#pragma unroll
    for (int ni = 0; ni < 4; ++ni) {
      int col = colbase + ni * 16 + tr;
      float bb = bv[col];
#pragma unroll
      for (int mi = 0; mi < 8; ++mi) {
        int row = rowbase + mi * 16 + quad * 4;
#pragma unroll
        for (int r = 0; r < 4; ++r)
          C[(int64_t)(row + r) * 1024 + col] =
              __float2bfloat16(acc[mi][ni][r] + bb);
      }
    }
  } else if (n0 < 1024) {  // K half
    __hip_bfloat16* C = Kc + (int64_t)z * 2048 * 1024;
#pragma unroll
    for (int ni = 0; ni < 4; ++ni) {
      int col = colbase + ni * 16 + tr;
      float bb = bv[col];
#pragma unroll
      for (int mi = 0; mi < 8; ++mi) {
        int row = rowbase + mi * 16 + quad * 4;
#pragma unroll
        for (int r = 0; r < 4; ++r)
          C[(int64_t)(row + r) * 1024 + col] =
              __float2bfloat16(acc[mi][ni][r] + bb);
      }
    }
  } else {  // V half -> LDS transpose in A0 (4 passes of 64 d-cols) -> Vt
    __hip_bfloat16* Vz = Vt + (int64_t)z * 1024 * 2048;
    const int d0 = n0 - 1024;
#pragma unroll
    for (int p = 0; p < 4; ++p) {
      __syncthreads();
      if (wn == p) {  // the 2 waves (wm=0,1) owning d-cols [p*64, p*64+64)
#pragma unroll
        for (int ni = 0; ni < 4; ++ni) {
          int cl = ni * 16 + tr;                       // pass-local d [0,64)
          float bb = bv[colbase + ni * 16 + tr];
#pragma unroll
          for (int mi = 0; mi < 8; ++mi) {
            int rl = wm * 128 + mi * 16 + quad * 4;    // block-local key
            __hip_bfloat16 h4[4];
#pragma unroll
            for (int r = 0; r < 4; ++r)
              h4[r] = __float2bfloat16(acc[mi][ni][r] + bb);
            *(ushort4*)(A0 + cl * 256 + (rl ^ ((cl & 31) << 3))) =
                *(const ushort4*)h4;
          }
        }
      }
      __syncthreads();
      const int dloc = tid >> 3;   // [0,64)
      const int sg = tid & 7;
#pragma unroll
      for (int i = 0; i < 4; ++i) {
        int seg = i * 8 + sg;      // [0,32) -> keys seg*8..seg*8+7
        bf16x8 v =
            *(const bf16x8*)(A0 + dloc * 256 + ((seg * 8) ^ ((dloc & 31) << 3)));
        *(bf16x8*)(Vz + (int64_t)(d0 + p * 64 + dloc) * 2048 + m0 + seg * 8) =
            v;
      }
    }
  }
}

// ------------------------ scores GEMM + fused exp --------------------------
// e = exp2(scale2 * (Q@Kc^T)) bf16; cols >= cnt -> 0. Row sums -> atomicAdd.
// BM=256, BN=128, BK=64, 8 waves (2M x 4N), per-wave C = 128x32.
// LDS 96KB: A0/A1=[256][64], B0/B1=[128][64].
__global__ __launch_bounds__(512, 2) void gemm_scores(
    const __hip_bfloat16* __restrict__ Qb, const __hip_bfloat16* __restrict__ Kc,
    __hip_bfloat16* __restrict__ Sc, float* __restrict__ rowsum,
    const int* __restrict__ cnt, const int* __restrict__ cnt_pad,
    float scale2) {
  const int z = blockIdx.z;
  const int f = blockIdx.x;
  const int xcd = f & 7, loc = f >> 3;
  const int m0 = (loc & 7) * 256;
  const int n0 = ((loc >> 3) * 8 + xcd) * 128;
  if (n0 >= cnt_pad[z]) return;
  const __hip_bfloat16* A = Qb + (int64_t)z * 2048 * 1024;
  const __hip_bfloat16* Bt = Kc + (int64_t)z * 2048 * 1024;

  const int tid = threadIdx.x;
  const int wave = tid >> 6, lane = tid & 63;
  const int quad = lane >> 4, tr = lane & 15, t7 = tr & 7;
  const int wm = wave >> 2, wn = wave & 3;

  __shared__ __hip_bfloat16 A0[16384];
  __shared__ __hip_bfloat16 A1[16384];
  __shared__ __hip_bfloat16 B0[8192];
  __shared__ __hip_bfloat16 B1[8192];

  const int srow = lane >> 3;
  const int kcs = ((lane & 7) ^ srow) * 8;

  const __hip_bfloat16* pA[2][2];
  const __hip_bfloat16* pB[2];
  int aoff[2][2], boff[2];
  {
#pragma unroll
    for (int h = 0; h < 2; ++h) {
#pragma unroll
      for (int j = 0; j < 2; ++j) {
        int chunk = wave * 2 + j;
        int rl = h * 128 + chunk * 8 + srow;
        pA[h][j] = A + (int64_t)(m0 + rl) * 1024 + kcs;
        aoff[h][j] = (h * 128 + chunk * 8) * 64;
      }
      int rlb = h * 64 + wave * 8 + srow;
      pB[h] = Bt + (int64_t)(n0 + rlb) * 1024 + kcs;
      boff[h] = (h * 64 + wave * 8) * 64;
    }
  }

  uint32_t aAd[2][2][2], bBd[2][2];
  {
    const uint32_t ab[2] = {laddr(A0), laddr(A1)};
    const uint32_t bb[2] = {laddr(B0), laddr(B1)};
#pragma unroll
    for (int buf = 0; buf < 2; ++buf)
#pragma unroll
      for (int s = 0; s < 2; ++s) {
        uint32_t col = (uint32_t)((((s << 2) | quad) ^ t7) * 16);
#pragma unroll
        for (int h = 0; h < 2; ++h)
          aAd[buf][h][s] = ab[buf] + (wm * 128 + h * 64 + tr) * 128 + col;
        bBd[buf][s] = bb[buf] + (wn * 32 + tr) * 128 + col;
      }
  }

  f32x4 acc[8][2];
#pragma unroll
  for (int mi = 0; mi < 8; ++mi)
#pragma unroll
    for (int ni = 0; ni < 2; ++ni) acc[mi][ni] = (f32x4){0.f, 0.f, 0.f, 0.f};

  bf16x8 af[4], bf[2];

#define STA(ARR, h, t)                                 \
  do {                                                 \
    async_cp16(pA[h][0] + (t) * 64, ARR + aoff[h][0]); \
    async_cp16(pA[h][1] + (t) * 64, ARR + aoff[h][1]); \
  } while (0)
#define STB(ARR, h, t) async_cp16(pB[h] + (t) * 64, ARR + boff[h])
#define DSA(buf, h, s)                      \
  do {                                      \
    DSR(af[0], aAd[buf][h][s], 0);          \
    DSR(af[1], aAd[buf][h][s], 2048);       \
    DSR(af[2], aAd[buf][h][s], 4096);       \
    DSR(af[3], aAd[buf][h][s], 6144);       \
  } while (0)
#define DSB(buf, s)                         \
  do {                                      \
    DSR(bf[0], bBd[buf][s], 0);             \
    DSR(bf[1], bBd[buf][s], 2048);          \
  } while (0)
#define MF(h)                                                                 \
  do {                                                                        \
    asm volatile("s_waitcnt lgkmcnt(0)" ::: "memory");                        \
    __builtin_amdgcn_sched_barrier(0);                                        \
    __builtin_amdgcn_s_setprio(1);                                            \
    _Pragma("unroll") for (int j = 0; j < 4; ++j)                             \
        _Pragma("unroll") for (int n = 0; n < 2; ++n) acc[(h)*4 + j][n] =     \
            __builtin_amdgcn_mfma_f32_16x16x32_bf16(af[j], bf[n],             \
                                                    acc[(h)*4 + j][n], 0, 0,  \
                                                    0);                       \
    __builtin_amdgcn_s_setprio(0);                                            \
  } while (0)

  STA(A0, 0, 0); STA(A0, 1, 0); STB(B0, 0, 0); STB(B0, 1, 0);
  STB(B1, 0, 1);
  VMW(1);
  BAR();

  for (int it = 0; it < 8; ++it) {
    const int t1 = 2 * it + 1;
    const int tn0 = (2 * it + 2 < 16) ? 2 * it + 2 : 15;
    const int tn1 = (2 * it + 3 < 16) ? 2 * it + 3 : 15;
    DSA(0, 0, 0); DSB(0, 0); STB(B1, 1, t1);  BAR(); MF(0); BAR();
    DSA(0, 1, 0);            STA(A1, 0, t1);  BAR(); MF(1); BAR();
    DSA(0, 0, 1); DSB(0, 1); STA(A1, 1, t1);  BAR(); MF(0); BAR();
    DSA(0, 1, 1);            STB(B0, 0, tn0); VMW(1); BAR(); MF(1); BAR();
    DSA(1, 0, 0); DSB(1, 0); STB(B0, 1, tn0); BAR(); MF(0); BAR();
    DSA(1, 1, 0);            STA(A0, 0, tn0); BAR(); MF(1); BAR();
    DSA(1, 0, 1); DSB(1, 1); STA(A0, 1, tn0); BAR(); MF(0); BAR();
    DSA(1, 1, 1);            STB(B1, 0, tn1); VMW(1); BAR(); MF(1); BAR();
  }
  asm volatile("s_waitcnt vmcnt(0)" ::: "memory");
  BAR();
#undef STA
#undef STB
#undef DSA
#undef DSB
#undef MF

  const int rowbase = m0 + wm * 128;
  const int colbase = n0 + wn * 32;
  const int cn = cnt[z];
  __hip_bfloat16* C = Sc + (int64_t)z * 2048 * 2048;

  float psum[8][4];
#pragma unroll
  for (int mi = 0; mi < 8; ++mi)
#pragma unroll
    for (int r = 0; r < 4; ++r) psum[mi][r] = 0.f;

#pragma unroll
  for (int ni = 0; ni < 2; ++ni) {
    int col = colbase + ni * 16 + tr;
    bool valid = (col < cn);
#pragma unroll
    for (int mi = 0; mi < 8; ++mi) {
      int row = rowbase + mi * 16 + quad * 4;
#pragma unroll
      for (int r = 0; r < 4; ++r) {
        float e = valid ? exp2f(acc[mi][ni][r] * scale2) : 0.f;
        C[(int64_t)(row + r) * 2048 + col] = __float2bfloat16(e);
        psum[mi][r] += e;
      }
    }
  }
#pragma unroll
  for (int off = 1; off <= 8; off <<= 1)
#pragma unroll
    for (int mi = 0; mi < 8; ++mi)
#pragma unroll
      for (int r = 0; r < 4; ++r)
        psum[mi][r] += __shfl_xor(psum[mi][r], off, 64);
  if (tr == 0) {
    float* rs = rowsum + z * 2048 + rowbase;
#pragma unroll
    for (int mi = 0; mi < 8; ++mi)
#pragma unroll
      for (int r = 0; r < 4; ++r)
        atomicAdd(&rs[mi * 16 + quad * 4 + r], psum[mi][r]);
  }
}

// --------------------------- PV GEMM + normalize ---------------------------
// out = (E @ Vt^T) / rowsum[row]  (fp32). K = cnt_pad[z]. BM=256, BN=128.
__global__ __launch_bounds__(512, 2) void gemm_pv(
    const __hip_bfloat16* __restrict__ Sc, const __hip_bfloat16* __restrict__ Vt,
    float* __restrict__ out, const float* __restrict__ rowsum,
    const int* __restrict__ cnt_pad) {
  const int z = blockIdx.z;
  const int f = blockIdx.x;
  const int m0 = (f >> 3) * 256;
  const int n0 = (f & 7) * 128;
  const int Ks = cnt_pad[z];
  const __hip_bfloat16* A = Sc + (int64_t)z * 2048 * 2048;
  const __hip_bfloat16* Bt = Vt + (int64_t)z * 1024 * 2048;

  const int tid = threadIdx.x;
  const int wave = tid >> 6, lane = tid & 63;
  const int quad = lane >> 4, tr = lane & 15, t7 = tr & 7;
  const int wm = wave >> 2, wn = wave & 3;

  __shared__ __hip_bfloat16 A0[16384];
  __shared__ __hip_bfloat16 A1[16384];
  __shared__ __hip_bfloat16 B0[8192];
  __shared__ __hip_bfloat16 B1[8192];

  const int srow = lane >> 3;
  const int kcs = ((lane & 7) ^ srow) * 8;

  const __hip_bfloat16* pA[2][2];
  const __hip_bfloat16* pB[2];
  int aoff[2][2], boff[2];
  {
#pragma unroll
    for (int h = 0; h < 2; ++h) {
#pragma unroll
      for (int j = 0; j < 2; ++j) {
        int chunk = wave * 2 + j;
        int rl = h * 128 + chunk * 8 + srow;
        pA[h][j] = A + (int64_t)(m0 + rl) * 2048 + kcs;
        aoff[h][j] = (h * 128 + chunk * 8) * 64;
      }
      int rlb = h * 64 + wave * 8 + srow;
      pB[h] = Bt + (int64_t)(n0 + rlb) * 2048 + kcs;
      boff[h] = (h * 64 + wave * 8) * 64;
    }
  }

  uint32_t aAd[2][2][2], bBd[2][2];
  {
    const uint32_t ab[2] = {laddr(A0), laddr(A1)};
    const uint32_t bb[2] = {laddr(B0), laddr(B1)};
#pragma unroll
    for (int buf = 0; buf < 2; ++buf)
#pragma unroll
      for (int s = 0; s < 2; ++s) {
        uint32_t col = (uint32_t)((((s << 2) | quad) ^ t7) * 16);
#pragma unroll
        for (int h = 0; h < 2; ++h)
          aAd[buf][h][s] = ab[buf] + (wm * 128 + h * 64 + tr) * 128 + col;
        bBd[buf][s] = bb[buf] + (wn * 32 + tr) * 128 + col;
      }
  }

  f32x4 acc[8][2];
#pragma unroll
  for (int mi = 0; mi < 8; ++mi)
#pragma unroll
    for (int ni = 0; ni < 2; ++ni) acc[mi][ni] = (f32x4){0.f, 0.f, 0.f, 0.f};

  bf16x8 af[4], bf[2];

#define STA(ARR, h, t)                                 \
  do {                                                 \
    async_cp16(pA[h][0] + (t) * 64, ARR + aoff[h][0]); \
    async_cp16(pA[h][1] + (t) * 64, ARR + aoff[h][1]); \
  } while (0)
#define STB(ARR, h, t) async_cp16(pB[h] + (t) * 64, ARR + boff[h])
#define DSA(buf, h, s)                      \
  do {                                      \
    DSR(af[0], aAd[buf][h][s], 0);          \
    DSR(af[1], aAd[buf][h][s], 2048);       \
    DSR(af[2], aAd[buf][h][s], 4096);       \
    DSR(af[3], aAd[buf][h][s], 6144);       \
  } while (0)
#define DSB(buf, s)                         \
  do {                                      \
    DSR(bf[0], bBd[buf][s], 0);             \
    DSR(bf[1], bBd[buf][s], 2048);          \
  } while (0)
#define MF(h)                                                                 \
  do {                                                                        \
    asm volatile("s_waitcnt lgkmcnt(0)" ::: "memory");                        \
    __builtin_amdgcn_sched_barrier(0);                                        \
    __builtin_amdgcn_s_setprio(1);                                            \
    _Pragma("unroll") for (int j = 0; j < 4; ++j)                             \
        _Pragma("unroll") for (int n = 0; n < 2; ++n) acc[(h)*4 + j][n] =     \
            __builtin_amdgcn_mfma_f32_16x16x32_bf16(af[j], bf[n],             \
                                                    acc[(h)*4 + j][n], 0, 0,  \
                                                    0);                       \
    __builtin_amdgcn_s_setprio(0);                                            \
  } while (0)

  const int NT = Ks >> 6;       // K-tiles (multiple of 4)
  const int NITER = NT >> 1;
  const int NTm1 = NT - 1;

  STA(A0, 0, 0); STA(A0, 1, 0); STB(B0, 0, 0); STB(B0, 1, 0);
  STB(B1, 0, 1);
  VMW(1);
  BAR();

  for (int it = 0; it < NITER; ++it) {
    const int t1 = 2 * it + 1;
    const int tn0 = (2 * it + 2 > NTm1) ? NTm1 : 2 * it + 2;
    const int tn1 = (2 * it + 3 > NTm1) ? NTm1 : 2 * it + 3;
    DSA(0, 0, 0); DSB(0, 0); STB(B1, 1, t1);  BAR(); MF(0); BAR();
    DSA(0, 1, 0);            STA(A1, 0, t1);  BAR(); MF(1); BAR();
    DSA(0, 0, 1); DSB(0, 1); STA(A1, 1, t1);  BAR(); MF(0); BAR();
    DSA(0, 1, 1);            STB(B0, 0, tn0); VMW(1); BAR(); MF(1); BAR();
    DSA(1, 0, 0); DSB(1, 0); STB(B0, 1, tn0); BAR(); MF(0); BAR();
    DSA(1, 1, 0);            STA(A0, 0, tn0); BAR(); MF(1); BAR();
    DSA(1, 0, 1); DSB(1, 1); STA(A0, 1, tn0); BAR(); MF(0); BAR();
    DSA(1, 1, 1);            STB(B1, 0, tn1); VMW(1); BAR(); MF(1); BAR();
  }
  asm volatile("s_waitcnt vmcnt(0)" ::: "memory");
  BAR();
#undef STA
#undef STB
#undef DSA
#undef DSB
#undef MF

  const int rowbase = m0 + wm * 128;
  const int colbase = n0 + wn * 32;
  const float* rs = rowsum + z * 2048 + rowbase;
  float invv[8][4];
#pragma unroll
  for (int mi = 0; mi < 8; ++mi)
#pragma unroll
    for (int r = 0; r < 4; ++r) invv[mi][r] = 1.0f / rs[mi * 16 + quad * 4 + r];

  float* C = out + (int64_t)z * 2048 * 1024;
#pragma unroll
  for (int ni = 0; ni < 2; ++ni) {
    int col = colbase + ni * 16 + tr;
#pragma unroll
    for (int mi = 0; mi < 8; ++mi) {
      int row = rowbase + mi * 16 + quad * 4;
#pragma unroll
      for (int r = 0; r < 4; ++r)
        C[(int64_t)(row + r) * 1024 + col] = acc[mi][ni][r] * invv[mi][r];
    }
  }
}

// ------------------------------- launcher ----------------------------------
extern "C" void kernel_launch(void* const* d_in, const int* in_sizes, int n_in,
                              void* d_out, int out_size, void* d_ws,
                              size_t ws_size, hipStream_t stream) {
  const float* X = (const float*)d_in[0];        // (4,2048,1024) fp32
  const int* mask = (const int*)d_in[1];         // (4,2048) bool->int32
  const float* W = (const float*)d_in[2];        // (1024,3072) fp32
  const float* bias = (const float*)d_in[3];     // (3072,) fp32
  float* out = (float*)d_out;                    // (4,2048,1024) fp32

  char* ws = (char*)d_ws;
  auto alloc = [&](size_t bytes) {
    char* p = ws;
    ws += (bytes + 255) & ~(size_t)255;
    return p;
  };
  __hip_bfloat16* Xb = (__hip_bfloat16*)alloc(8192ULL * 1024 * 2);      // 16.8 MB
  __hip_bfloat16* Wt = (__hip_bfloat16*)alloc(3072ULL * 1024 * 2);      //  6.3 MB
  __hip_bfloat16* Q = (__hip_bfloat16*)alloc(8192ULL * 1024 * 2);       // 16.8 MB
  __hip_bfloat16* Kc = (__hip_bfloat16*)alloc(4ULL * 2048 * 1024 * 2);  // 16.8 MB
  __hip_bfloat16* Vt = (__hip_bfloat16*)alloc(4ULL * 1024 * 2048 * 2);  // 16.8 MB
  __hip_bfloat16* Sc = (__hip_bfloat16*)alloc(4ULL * 2048 * 2048 * 2);  // 33.6 MB
  float* rowsum = (float*)alloc(8192ULL * 4);                           // 32 KB
  int* idx = (int*)alloc(4ULL * 2048 * 4);
  int* cnt = (int*)alloc(64);
  int* cnt_pad = (int*)alloc(64);

  // 0) rowsum = 0 (ws is poisoned 0xAA before every launch)
  hipMemsetAsync(rowsum, 0, 8192ULL * 4, stream);
  // 1) X -> bf16
  cvt_f32_bf16<<<8192, 256, 0, stream>>>(X, Xb, 8192 * 1024);
  // 2) W -> W^T bf16  (Bt layout [N][K])
  transpose_cvt_f32<<<dim3(96, 32, 1), dim3(32, 8), 0, stream>>>(W, 3072, Wt,
                                                                 1024);
  // 3) mask -> compacted index list (cnt_pad 256-aligned)
  mask_scan<<<4, 256, 0, stream>>>(mask, idx, cnt, cnt_pad);
  // 4) merged Q + K + V^T, 256x256 8-phase
  gemm_qkv<<<dim3(96, 1, 4), 512, 0, stream>>>(Xb, Wt, bias, idx, cnt,
                                               cnt_pad, Q, Kc, Vt);
  // 5) E = exp2(log2e/32 * Q@Kc^T) -> bf16, rowsum += per-row sums
  gemm_scores<<<dim3(128, 1, 4), 512, 0, stream>>>(
      Q, Kc, Sc, rowsum, cnt, cnt_pad, 0.03125f * 1.4426950408889634f);
  // 6) out = (E @ Vt^T) / rowsum  (fp32, K = cnt_pad)
  gemm_pv<<<dim3(64, 1, 4), 512, 0, stream>>>(Sc, Vt, out, rowsum, cnt_pad);
}

// Round 5
// 204.658 us; speedup vs baseline: 1.3233x; 1.1627x over previous
//
#include <hip/hip_runtime.h>
#include <hip/hip_bf16.h>
#include <stdint.h>

// ---------------------------------------------------------------------------
// SelfAttention: QKV = X@W + b ; S = QK^T/32 (mask -> -inf) ; O = softmax(S)@V
// B=4, S=2048, H=1024.  bf16 MFMA path.
// R13: revert to R9 base (128x128 tiles, 256thr, BK=64 dbuf prefetch) --
//     the 256^2 8-phase structure (R10-12) is grid-quantization-bound at
//     these shapes (384 coarse blocks / 256 CUs = 2 rounds). Two edits:
//     (a) scores/pv widened 128x64 -> 128x128 (same k-loop profile as qkv;
//         they were ~450 TF due to half the MFMA per staged byte).
//     (b) all fragment LDS reads are inline-asm ds_read_b128 with explicit
//         lgkmcnt(0)+sched_barrier gates (R12-proven), so the counted
//         vmcnt(8) prefetch gate is the ONLY DMA wait -- removes the
//         compiler's implicit vmcnt(0) drain that made R9 ~= R8.
// ---------------------------------------------------------------------------

typedef __attribute__((ext_vector_type(8))) short bf16x8;   // 8 bf16 = 4 VGPRs
typedef __attribute__((ext_vector_type(4))) float f32x4;

__device__ __forceinline__ void async_cp16(const void* g, void* l) {
  __builtin_amdgcn_global_load_lds(
      (const __attribute__((address_space(1))) void*)g,
      (__attribute__((address_space(3))) void*)l, 16, 0, 0);
}

__device__ __forceinline__ uint32_t laddr(const void* p) {
  return (uint32_t)(uintptr_t)(const __attribute__((address_space(3))) void*)p;
}

#define FENCE() asm volatile("" ::: "memory")
#define BAR()                           \
  do {                                  \
    FENCE();                            \
    __builtin_amdgcn_s_barrier();       \
    FENCE();                            \
  } while (0)
#define VMW(N) asm volatile("s_waitcnt vmcnt(" #N ")" ::: "memory")
#define LGKM0()                                            \
  do {                                                     \
    asm volatile("s_waitcnt lgkmcnt(0)" ::: "memory");     \
    __builtin_amdgcn_sched_barrier(0);                     \
  } while (0)
// asm ds_read_b128 with literal byte offset; no memory operand on purpose.
#define DSR(dst, a, OFF) \
  asm volatile("ds_read_b128 %0, %1 offset:" #OFF : "=v"(dst) : "v"(a))

// --------------------------- fp32 -> bf16 convert ---------------------------
__global__ void cvt_f32_bf16(const float* __restrict__ s,
                             __hip_bfloat16* __restrict__ d, int n) {
  int i = (blockIdx.x * blockDim.x + threadIdx.x) * 4;
  if (i >= n) return;
  float4 f = *(const float4*)(s + i);
  __hip_bfloat16 o[4];
  o[0] = __float2bfloat16(f.x);
  o[1] = __float2bfloat16(f.y);
  o[2] = __float2bfloat16(f.z);
  o[3] = __float2bfloat16(f.w);
  *(ushort4*)(d + i) = *(const ushort4*)o;
}

// -------------------- fp32 -> bf16 transposed (W -> W^T) --------------------
__global__ void transpose_cvt_f32(const float* __restrict__ src, int srcld,
                                  __hip_bfloat16* __restrict__ dst, int dstld) {
  __shared__ float tile[32][33];
  int bx = blockIdx.x * 32;   // src col
  int by = blockIdx.y * 32;   // src row
  int tx = threadIdx.x, ty = threadIdx.y;
#pragma unroll
  for (int j = 0; j < 4; ++j)
    tile[ty + j * 8][tx] = src[(int64_t)(by + ty + j * 8) * srcld + bx + tx];
  __syncthreads();
#pragma unroll
  for (int j = 0; j < 4; ++j)
    dst[(int64_t)(bx + ty + j * 8) * dstld + by + tx] =
        __float2bfloat16(tile[tx][ty + j * 8]);
}

// ------------------------------ mask scan ----------------------------------
__global__ __launch_bounds__(256) void mask_scan(const int* __restrict__ mask,
                                                 int* __restrict__ idx,
                                                 int* __restrict__ cnt,
                                                 int* __restrict__ cnt_pad) {
  const int b = blockIdx.x;
  mask += b * 2048;
  idx += b * 2048;
  const int t = threadIdx.x;
  const int lane = t & 63, wave = t >> 6;

  int keep[8];
  int local = 0;
#pragma unroll
  for (int j = 0; j < 8; ++j) {
    keep[j] = (mask[t * 8 + j] == 0);
    local += keep[j];
  }
  int pre = local;  // inclusive wave scan
#pragma unroll
  for (int off = 1; off <= 32; off <<= 1) {
    int n = __shfl_up(pre, off, 64);
    if (lane >= off) pre += n;
  }
  __shared__ int wsum[4];
  if (lane == 63) wsum[wave] = pre;
  __syncthreads();
  int base = 0;
  for (int w = 0; w < wave; ++w) base += wsum[w];
  int excl = base + pre - local;
#pragma unroll
  for (int j = 0; j < 8; ++j)
    if (keep[j]) idx[excl++] = t * 8 + j;
  if (t == 255) {
    int tot = base + pre;
    cnt[b] = tot;
    cnt_pad[b] = (tot + 127) & ~127;
  }
}

// --------------------------- merged Q+K+V GEMM -----------------------------
// grid (384, 1, B).  Swizzled flat id: xcd=f&7, loc=f>>3 in [0,48):
//   m_idx = (loc&7)*2 + (xcd>>2); n_idx = (loc>>3)*4 + (xcd&3) in [0,24)
// n_idx<8:  Q  = Xb[z] @ Wt[0:1024]^T + b      (all 2048 rows)
// n_idx>=8: KV = gather(Xb[z], idx) @ Wt[1024:3072]^T + b, rows < cnt_pad[z]
// 128x128 tile, 256 thr, BK=64, dbuf prefetch, asm ds_read fragments.
__global__ __launch_bounds__(256) void gemm_qkv(
    const __hip_bfloat16* __restrict__ Xb, const __hip_bfloat16* __restrict__ Wt,
    const float* __restrict__ bias, const int* __restrict__ idx,
    const int* __restrict__ cnt, const int* __restrict__ cnt_pad,
    __hip_bfloat16* __restrict__ Q, __hip_bfloat16* __restrict__ Kc,
    __hip_bfloat16* __restrict__ Vt) {
  const int z = blockIdx.z;
  const int f = blockIdx.x;
  const int xcd = f & 7, loc = f >> 3;
  const int m0 = ((loc & 7) * 2 + (xcd >> 2)) * 128;
  const int n_idx = (loc >> 3) * 4 + (xcd & 3);
  const bool isQ = (n_idx < 8);
  if (!isQ && m0 >= cnt_pad[z]) return;
  const int n0 = (isQ ? n_idx : n_idx - 8) * 128;
  const __hip_bfloat16* A = Xb + (int64_t)z * 2048 * 1024;
  const __hip_bfloat16* Bt = Wt + (isQ ? 0 : (int64_t)1024 * 1024);
  const float* bv = bias + (isQ ? 0 : 1024);

  const int tid = threadIdx.x;
  const int wave = tid >> 6, lane = tid & 63;
  const int quad = lane >> 4, tr = lane & 15, t7 = tr & 7;
  const int wm = wave & 1, wn = wave >> 1;

  // 2 bufs x (lsA 8192 el + lsB 8192 el) = 64KB; V-epilogue reuses as
  // vt[128][136].
  __shared__ __hip_bfloat16 ls[32768];

  // 32 chunks of 1KB (8 rows x 128B each): 0..15 = A, 16..31 = B. 8/wave.
  const __hip_bfloat16* gsrc[8];
  int loff[8];  // element offset within one buffer
  {
    const int srow = lane >> 3;                 // 0..7
    const int kcs = (((lane & 7) ^ srow) * 8);  // swizzled k-chunk (elements)
    const int cz = isQ ? 0 : cnt[z];
    const int* idxz = idx + z * 2048;
#pragma unroll
    for (int cc = 0; cc < 8; ++cc) {
      int c = wave * 8 + cc;
      int isA = (c < 16);
      int cr = isA ? c : (c - 16);
      int row = cr * 8 + srow;
      if (isA) {
        int ar = m0 + row;
        if (!isQ) ar = (ar < cz) ? idxz[ar] : 0;
        gsrc[cc] = A + (int64_t)ar * 1024 + kcs;
      } else {
        gsrc[cc] = Bt + (int64_t)(n0 + row) * 1024 + kcs;
      }
      loff[cc] = (isA ? 0 : 8192) + cr * 512;
    }
  }

  // LDS byte addrs for asm fragment reads (buf, k-half w).
  uint32_t aAd[2][2], bBd[2][2];
  {
    uint32_t base = laddr(ls);
#pragma unroll
    for (int b = 0; b < 2; ++b)
#pragma unroll
      for (int w = 0; w < 2; ++w) {
        uint32_t col = (uint32_t)(((((w << 2) | quad)) ^ t7) * 16);
        aAd[b][w] = base + b * 32768 + (wm * 64 + tr) * 128 + col;
        bBd[b][w] = base + b * 32768 + 16384 + (wn * 64 + tr) * 128 + col;
      }
  }

  f32x4 acc[4][4];
#pragma unroll
  for (int mi = 0; mi < 4; ++mi)
#pragma unroll
    for (int ni = 0; ni < 4; ++ni) acc[mi][ni] = (f32x4){0.f, 0.f, 0.f, 0.f};

  bf16x8 af[4], bf[4];

#define STAGE(BUF, k0)                                            \
  do {                                                            \
    _Pragma("unroll") for (int cc = 0; cc < 8; ++cc)              \
        async_cp16(gsrc[cc] + (k0), ls + (BUF)*16384 + loff[cc]); \
  } while (0)
#define COMP(BUF)                                                             \
  do {                                                                        \
    _Pragma("unroll") for (int w = 0; w < 2; ++w) {                           \
      DSR(af[0], aAd[BUF][w], 0);                                             \
      DSR(af[1], aAd[BUF][w], 2048);                                          \
      DSR(af[2], aAd[BUF][w], 4096);                                          \
      DSR(af[3], aAd[BUF][w], 6144);                                          \
      DSR(bf[0], bBd[BUF][w], 0);                                             \
      DSR(bf[1], bBd[BUF][w], 2048);                                          \
      DSR(bf[2], bBd[BUF][w], 4096);                                          \
      DSR(bf[3], bBd[BUF][w], 6144);                                          \
      LGKM0();                                                                \
      _Pragma("unroll") for (int mi = 0; mi < 4; ++mi)                        \
          _Pragma("unroll") for (int ni = 0; ni < 4; ++ni) acc[mi][ni] =      \
              __builtin_amdgcn_mfma_f32_16x16x32_bf16(af[mi], bf[ni],         \
                                                      acc[mi][ni], 0, 0, 0);  \
    }                                                                         \
  } while (0)

  STAGE(0, 0);
  for (int it = 0; it < 8; ++it) {
    STAGE(1, (2 * it + 1) * 64);
    VMW(8); BAR();
    COMP(0);
    BAR();
    if (it < 7) {
      STAGE(0, (2 * it + 2) * 64);
      VMW(8);
    } else {
      VMW(0);
    }
    BAR();
    COMP(1);
    BAR();
  }
#undef STAGE
#undef COMP

  // Epilogue. D element (row,col) in 16x16 tile = (quad*4 + r, tr)  [m89]
  const int rowbase = m0 + wm * 64;
  const int colbase = n0 + wn * 64;
  if (isQ) {
    __hip_bfloat16* C = Q + (int64_t)z * 2048 * 1024;
#pragma unroll
    for (int ni = 0; ni < 4; ++ni) {
      int col = colbase + ni * 16 + tr;
      float bb = bv[col];
#pragma unroll
      for (int mi = 0; mi < 4; ++mi) {
        int row = rowbase + mi * 16 + quad * 4;
#pragma unroll
        for (int r = 0; r < 4; ++r)
          C[(int64_t)(row + r) * 1024 + col] =
              __float2bfloat16(acc[mi][ni][r] + bb);
      }
    }
  } else if (n0 < 1024) {  // K half
    __hip_bfloat16* C = Kc + (int64_t)z * 2048 * 1024;
#pragma unroll
    for (int ni = 0; ni < 4; ++ni) {
      int col = colbase + ni * 16 + tr;
      float bb = bv[col];
#pragma unroll
      for (int mi = 0; mi < 4; ++mi) {
        int row = rowbase + mi * 16 + quad * 4;
#pragma unroll
        for (int r = 0; r < 4; ++r)
          C[(int64_t)(row + r) * 1024 + col] =
              __float2bfloat16(acc[mi][ni][r] + bb);
      }
    }
  } else {  // V half -> LDS transpose -> coalesced Vt rows
    __syncthreads();
#pragma unroll
    for (int ni = 0; ni < 4; ++ni) {
      int cl = wn * 64 + ni * 16 + tr;  // block-local d
      float bb = bv[colbase + ni * 16 + tr];
#pragma unroll
      for (int mi = 0; mi < 4; ++mi) {
        int rl = wm * 64 + mi * 16 + quad * 4;  // block-local key
        __hip_bfloat16 h[4];
#pragma unroll
        for (int r = 0; r < 4; ++r) h[r] = __float2bfloat16(acc[mi][ni][r] + bb);
        *(ushort4*)(ls + cl * 136 + rl) = *(const ushort4*)h;
      }
    }
    __syncthreads();
    __hip_bfloat16* Vz = Vt + (int64_t)z * 1024 * 2048;
    const int d0 = n0 - 1024;
    const int seg = tid & 15;
#pragma unroll
    for (int p = 0; p < 8; ++p) {
      int d = p * 16 + (tid >> 4);
      bf16x8 v = *(const bf16x8*)(ls + d * 136 + seg * 8);
      *(bf16x8*)(Vz + (int64_t)(d0 + d) * 2048 + m0 + seg * 8) = v;
    }
  }
}

// ------------------------ scores GEMM + fused exp --------------------------
// e = exp2(scale2 * (Q@Kc^T)) bf16; cols >= cnt -> 0. Row sums -> atomicAdd.
// 128x128 tile (was 128x64), BK=64, dbuf prefetch, asm ds_read fragments.
// grid (256,1,4): m_idx=(loc&7)*2+(xcd>>2) in [0,16); n_idx=(loc>>3)*4+(xcd&3).
__global__ __launch_bounds__(256) void gemm_scores(
    const __hip_bfloat16* __restrict__ Qb, const __hip_bfloat16* __restrict__ Kc,
    __hip_bfloat16* __restrict__ Sc, float* __restrict__ rowsum,
    const int* __restrict__ cnt, const int* __restrict__ cnt_pad,
    float scale2) {
  const int z = blockIdx.z;
  const int f = blockIdx.x;
  const int xcd = f & 7, loc = f >> 3;
  const int m0 = ((loc & 7) * 2 + (xcd >> 2)) * 128;
  const int n0 = ((loc >> 3) * 4 + (xcd & 3)) * 128;
  if (n0 >= cnt_pad[z]) return;
  const __hip_bfloat16* A = Qb + (int64_t)z * 2048 * 1024;
  const __hip_bfloat16* Bt = Kc + (int64_t)z * 2048 * 1024;

  const int tid = threadIdx.x;
  const int wave = tid >> 6, lane = tid & 63;
  const int quad = lane >> 4, tr = lane & 15, t7 = tr & 7;
  const int wm = wave & 1, wn = wave >> 1;

  __shared__ __hip_bfloat16 ls[32768];

  const __hip_bfloat16* gsrc[8];
  int loff[8];
  {
    const int srow = lane >> 3;
    const int kcs = (((lane & 7) ^ srow) * 8);
#pragma unroll
    for (int cc = 0; cc < 8; ++cc) {
      int c = wave * 8 + cc;
      int isA = (c < 16);
      int cr = isA ? c : (c - 16);
      int row = cr * 8 + srow;
      gsrc[cc] = isA ? (A + (int64_t)(m0 + row) * 1024 + kcs)
                     : (Bt + (int64_t)(n0 + row) * 1024 + kcs);
      loff[cc] = (isA ? 0 : 8192) + cr * 512;
    }
  }

  uint32_t aAd[2][2], bBd[2][2];
  {
    uint32_t base = laddr(ls);
#pragma unroll
    for (int b = 0; b < 2; ++b)
#pragma unroll
      for (int w = 0; w < 2; ++w) {
        uint32_t col = (uint32_t)(((((w << 2) | quad)) ^ t7) * 16);
        aAd[b][w] = base + b * 32768 + (wm * 64 + tr) * 128 + col;
        bBd[b][w] = base + b * 32768 + 16384 + (wn * 64 + tr) * 128 + col;
      }
  }

  f32x4 acc[4][4];
#pragma unroll
  for (int mi = 0; mi < 4; ++mi)
#pragma unroll
    for (int ni = 0; ni < 4; ++ni) acc[mi][ni] = (f32x4){0.f, 0.f, 0.f, 0.f};

  bf16x8 af[4], bf[4];

#define STAGE(BUF, k0)                                            \
  do {                                                            \
    _Pragma("unroll") for (int cc = 0; cc < 8; ++cc)              \
        async_cp16(gsrc[cc] + (k0), ls + (BUF)*16384 + loff[cc]); \
  } while (0)
#define COMP(BUF)                                                             \
  do {                                                                        \
    _Pragma("unroll") for (int w = 0; w < 2; ++w) {                           \
      DSR(af[0], aAd[BUF][w], 0);                                             \
      DSR(af[1], aAd[BUF][w], 2048);                                          \
      DSR(af[2], aAd[BUF][w], 4096);                                          \
      DSR(af[3], aAd[BUF][w], 6144);                                          \
      DSR(bf[0], bBd[BUF][w], 0);                                             \
      DSR(bf[1], bBd[BUF][w], 2048);                                          \
      DSR(bf[2], bBd[BUF][w], 4096);                                          \
      DSR(bf[3], bBd[BUF][w], 6144);                                          \
      LGKM0();                                                                \
      _Pragma("unroll") for (int mi = 0; mi < 4; ++mi)                        \
          _Pragma("unroll") for (int ni = 0; ni < 4; ++ni) acc[mi][ni] =      \
              __builtin_amdgcn_mfma_f32_16x16x32_bf16(af[mi], bf[ni],         \
                                                      acc[mi][ni], 0, 0, 0);  \
    }                                                                         \
  } while (0)

  STAGE(0, 0);
  for (int it = 0; it < 8; ++it) {
    STAGE(1, (2 * it + 1) * 64);
    VMW(8); BAR();
    COMP(0);
    BAR();
    if (it < 7) {
      STAGE(0, (2 * it + 2) * 64);
      VMW(8);
    } else {
      VMW(0);
    }
    BAR();
    COMP(1);
    BAR();
  }
#undef STAGE
#undef COMP

  const int rowbase = m0 + wm * 64;
  const int colbase = n0 + wn * 64;
  const int cn = cnt[z];
  __hip_bfloat16* C = Sc + (int64_t)z * 2048 * 2048;

  float psum[4][4];
#pragma unroll
  for (int mi = 0; mi < 4; ++mi)
#pragma unroll
    for (int r = 0; r < 4; ++r) psum[mi][r] = 0.f;

#pragma unroll
  for (int ni = 0; ni < 4; ++ni) {
    int col = colbase + ni * 16 + tr;
    bool valid = (col < cn);
#pragma unroll
    for (int mi = 0; mi < 4; ++mi) {
      int row = rowbase + mi * 16 + quad * 4;
#pragma unroll
      for (int r = 0; r < 4; ++r) {
        float e = valid ? exp2f(acc[mi][ni][r] * scale2) : 0.f;
        C[(int64_t)(row + r) * 2048 + col] = __float2bfloat16(e);
        psum[mi][r] += e;
      }
    }
  }
#pragma unroll
  for (int off = 1; off <= 8; off <<= 1)
#pragma unroll
    for (int mi = 0; mi < 4; ++mi)
#pragma unroll
      for (int r = 0; r < 4; ++r)
        psum[mi][r] += __shfl_xor(psum[mi][r], off, 64);
  if (tr == 0) {
    float* rs = rowsum + z * 2048 + rowbase;
#pragma unroll
    for (int mi = 0; mi < 4; ++mi)
#pragma unroll
      for (int r = 0; r < 4; ++r)
        atomicAdd(&rs[mi * 16 + quad * 4 + r], psum[mi][r]);
  }
}

// --------------------------- PV GEMM + normalize ---------------------------
// out = (E @ Vt^T) / rowsum[row]  (fp32). K = cnt_pad[z]. 128x128 tile,
// BK=64, dbuf prefetch, asm ds_read fragments. grid (128,1,4).
__global__ __launch_bounds__(256) void gemm_pv(
    const __hip_bfloat16* __restrict__ Sc, const __hip_bfloat16* __restrict__ Vt,
    float* __restrict__ out, const float* __restrict__ rowsum,
    const int* __restrict__ cnt_pad) {
  const int z = blockIdx.z;
  const int f = blockIdx.x;
  const int xcd = f & 7, loc = f >> 3;
  const int m0 = ((loc & 7) * 2 + (xcd >> 2)) * 128;
  const int n0 = ((loc >> 3) * 4 + (xcd & 3)) * 128;
  const int Ks = cnt_pad[z];
  const __hip_bfloat16* A = Sc + (int64_t)z * 2048 * 2048;
  const __hip_bfloat16* Bt = Vt + (int64_t)z * 1024 * 2048;

  const int tid = threadIdx.x;
  const int wave = tid >> 6, lane = tid & 63;
  const int quad = lane >> 4, tr = lane & 15, t7 = tr & 7;
  const int wm = wave & 1, wn = wave >> 1;

  __shared__ __hip_bfloat16 ls[32768];

  const __hip_bfloat16* gsrc[8];
  int loff[8];
  {
    const int srow = lane >> 3;
    const int kcs = (((lane & 7) ^ srow) * 8);
#pragma unroll
    for (int cc = 0; cc < 8; ++cc) {
      int c = wave * 8 + cc;
      int isA = (c < 16);
      int cr = isA ? c : (c - 16);
      int row = cr * 8 + srow;
      gsrc[cc] = isA ? (A + (int64_t)(m0 + row) * 2048 + kcs)
                     : (Bt + (int64_t)(n0 + row) * 2048 + kcs);
      loff[cc] = (isA ? 0 : 8192) + cr * 512;
    }
  }

  uint32_t aAd[2][2], bBd[2][2];
  {
    uint32_t base = laddr(ls);
#pragma unroll
    for (int b = 0; b < 2; ++b)
#pragma unroll
      for (int w = 0; w < 2; ++w) {
        uint32_t col = (uint32_t)(((((w << 2) | quad)) ^ t7) * 16);
        aAd[b][w] = base + b * 32768 + (wm * 64 + tr) * 128 + col;
        bBd[b][w] = base + b * 32768 + 16384 + (wn * 64 + tr) * 128 + col;
      }
  }

  f32x4 acc[4][4];
#pragma unroll
  for (int mi = 0; mi < 4; ++mi)
#pragma unroll
    for (int ni = 0; ni < 4; ++ni) acc[mi][ni] = (f32x4){0.f, 0.f, 0.f, 0.f};

  bf16x8 af[4], bf[4];

#define STAGE(BUF, k0)                                            \
  do {                                                            \
    _Pragma("unroll") for (int cc = 0; cc < 8; ++cc)              \
        async_cp16(gsrc[cc] + (k0), ls + (BUF)*16384 + loff[cc]); \
  } while (0)
#define COMP(BUF)                                                             \
  do {                                                                        \
    _Pragma("unroll") for (int w = 0; w < 2; ++w) {                           \
      DSR(af[0], aAd[BUF][w], 0);                                             \
      DSR(af[1], aAd[BUF][w], 2048);                                          \
      DSR(af[2], aAd[BUF][w], 4096);                                          \
      DSR(af[3], aAd[BUF][w], 6144);                                          \
      DSR(bf[0], bBd[BUF][w], 0);                                             \
      DSR(bf[1], bBd[BUF][w], 2048);                                          \
      DSR(bf[2], bBd[BUF][w], 4096);                                          \
      DSR(bf[3], bBd[BUF][w], 6144);                                          \
      LGKM0();                                                                \
      _Pragma("unroll") for (int mi = 0; mi < 4; ++mi)                        \
          _Pragma("unroll") for (int ni = 0; ni < 4; ++ni) acc[mi][ni] =      \
              __builtin_amdgcn_mfma_f32_16x16x32_bf16(af[mi], bf[ni],         \
                                                      acc[mi][ni], 0, 0, 0);  \
    }                                                                         \
  } while (0)

  const int NP = Ks >> 7;  // K-tile pairs (cnt_pad is 128-aligned)
  STAGE(0, 0);
  for (int it = 0; it < NP; ++it) {
    STAGE(1, (2 * it + 1) * 64);
    VMW(8); BAR();
    COMP(0);
    BAR();
    if (it + 1 < NP) {
      STAGE(0, (2 * it + 2) * 64);
      VMW(8);
    } else {
      VMW(0);
    }
    BAR();
    COMP(1);
    BAR();
  }
#undef STAGE
#undef COMP

  const int rowbase = m0 + wm * 64;
  const int colbase = n0 + wn * 64;
  const float* rs = rowsum + z * 2048 + rowbase;
  float invv[4][4];
#pragma unroll
  for (int mi = 0; mi < 4; ++mi)
#pragma unroll
    for (int r = 0; r < 4; ++r) invv[mi][r] = 1.0f / rs[mi * 16 + quad * 4 + r];

  float* C = out + (int64_t)z * 2048 * 1024;
#pragma unroll
  for (int ni = 0; ni < 4; ++ni) {
    int col = colbase + ni * 16 + tr;
#pragma unroll
    for (int mi = 0; mi < 4; ++mi) {
      int row = rowbase + mi * 16 + quad * 4;
#pragma unroll
      for (int r = 0; r < 4; ++r)
        C[(int64_t)(row + r) * 1024 + col] = acc[mi][ni][r] * invv[mi][r];
    }
  }
}

// ------------------------------- launcher ----------------------------------
extern "C" void kernel_launch(void* const* d_in, const int* in_sizes, int n_in,
                              void* d_out, int out_size, void* d_ws,
                              size_t ws_size, hipStream_t stream) {
  const float* X = (const float*)d_in[0];        // (4,2048,1024) fp32
  const int* mask = (const int*)d_in[1];         // (4,2048) bool->int32
  const float* W = (const float*)d_in[2];        // (1024,3072) fp32
  const float* bias = (const float*)d_in[3];     // (3072,) fp32
  float* out = (float*)d_out;                    // (4,2048,1024) fp32

  char* ws = (char*)d_ws;
  auto alloc = [&](size_t bytes) {
    char* p = ws;
    ws += (bytes + 255) & ~(size_t)255;
    return p;
  };
  __hip_bfloat16* Xb = (__hip_bfloat16*)alloc(8192ULL * 1024 * 2);      // 16.8 MB
  __hip_bfloat16* Wt = (__hip_bfloat16*)alloc(3072ULL * 1024 * 2);      //  6.3 MB
  __hip_bfloat16* Q = (__hip_bfloat16*)alloc(8192ULL * 1024 * 2);       // 16.8 MB
  __hip_bfloat16* Kc = (__hip_bfloat16*)alloc(4ULL * 2048 * 1024 * 2);  // 16.8 MB
  __hip_bfloat16* Vt = (__hip_bfloat16*)alloc(4ULL * 1024 * 2048 * 2);  // 16.8 MB
  __hip_bfloat16* Sc = (__hip_bfloat16*)alloc(4ULL * 2048 * 2048 * 2);  // 33.6 MB
  float* rowsum = (float*)alloc(8192ULL * 4);                           // 32 KB
  int* idx = (int*)alloc(4ULL * 2048 * 4);
  int* cnt = (int*)alloc(64);
  int* cnt_pad = (int*)alloc(64);

  // 0) rowsum = 0 (ws is poisoned 0xAA before every launch)
  hipMemsetAsync(rowsum, 0, 8192ULL * 4, stream);
  // 1) X -> bf16
  cvt_f32_bf16<<<8192, 256, 0, stream>>>(X, Xb, 8192 * 1024);
  // 2) W -> W^T bf16  (Bt layout [N][K])
  transpose_cvt_f32<<<dim3(96, 32, 1), dim3(32, 8), 0, stream>>>(W, 3072, Wt,
                                                                 1024);
  // 3) mask -> compacted index list (cnt_pad 128-aligned)
  mask_scan<<<4, 256, 0, stream>>>(mask, idx, cnt, cnt_pad);
  // 4) merged Q + K + V^T (swizzled; V transposed via LDS in epilogue)
  gemm_qkv<<<dim3(384, 1, 4), 256, 0, stream>>>(Xb, Wt, bias, idx, cnt,
                                                cnt_pad, Q, Kc, Vt);
  // 5) E = exp2(log2e/32 * Q@Kc^T) -> bf16, rowsum += per-row sums
  gemm_scores<<<dim3(256, 1, 4), 256, 0, stream>>>(
      Q, Kc, Sc, rowsum, cnt, cnt_pad, 0.03125f * 1.4426950408889634f);
  // 6) out = (E @ Vt^T) / rowsum  (fp32, K = cnt_pad)
  gemm_pv<<<dim3(128, 1, 4), 256, 0, stream>>>(Sc, Vt, out, rowsum, cnt_pad);
}